// Round 1
// 547.061 us; speedup vs baseline: 1.0036x; 1.0036x over previous
//
#include <hip/hip_runtime.h>
#include <hip/hip_bf16.h>

typedef __attribute__((ext_vector_type(8))) short bf16x8;
typedef __attribute__((ext_vector_type(4))) short bf16x4;
typedef __attribute__((ext_vector_type(4))) float f32x4;
typedef __hip_bfloat16 bf16;
typedef unsigned short u16;

#define B_ 4
#define S_ 2048
#define D_ 1024
#define F_ 4096
#define H_ 16
#define MROWS 8192   // B_*S_
// 1/sqrt(dk) * log2(e), folded into the q-slice of the QKV GEMM epilogue
#define QSCALE 0.18033688011116012f

// ---------------- helpers ----------------
// pack 2 f32 -> 2 bf16 (round-half-up): 2 adds + 1 v_perm
__device__ __forceinline__ unsigned pkbf(float lo, float hi){
  union{float f; unsigned u;} a, b; a.f = lo; b.f = hi;
  return __builtin_amdgcn_perm(b.u + 0x8000u, a.u + 0x8000u, 0x07060302);
}
// single f32 -> bf16 bits (round-half-up): 2 VALU
__device__ __forceinline__ u16 bfrnd(float f){
  union{float ff; unsigned u;} c; c.ff = f;
  return (u16)((c.u + 0x8000u) >> 16);
}
// async global->LDS, 16B per lane; LDS dest = wave-uniform base + lane*16
__device__ __forceinline__ void gll16(const bf16* gp, u16* lp){
  __builtin_amdgcn_global_load_lds(
      (const __attribute__((address_space(1))) void*)gp,
      (__attribute__((address_space(3))) void*)lp, 16, 0, 0);
}

// ---------------- fused prep: 6 weight transposes + bias concat, ONE launch ----------------
// transpose semantics: W[K][N] f32 -> WT[N][K] bf16
struct PrepArgs { const float* w[6]; const float* b[3]; };
__global__ __launch_bounds__(256) void prep(
    PrepArgs pa, bf16* __restrict__ wqkvoT, bf16* __restrict__ w1T,
    bf16* __restrict__ w2T, float* __restrict__ bqkv)
{
  __shared__ float tl[32][33];
  const int bid = blockIdx.x, tid = threadIdx.x;
  const int x = tid&31, y = tid>>5;
  if (bid < 12288) {
    const float* W; bf16* dst; int K, N, nb, kb;
    if (bid < 4096)      { int wi=bid>>10, t=bid&1023; W=pa.w[wi]; dst=wqkvoT+(size_t)wi*1048576; K=1024; N=1024; nb=t&31;  kb=t>>5; }
    else if (bid < 8192) { int t=bid-4096;             W=pa.w[4];  dst=w1T;  K=1024; N=4096; nb=t&127; kb=t>>7; }
    else                 { int t=bid-8192;             W=pa.w[5];  dst=w2T;  K=4096; N=1024; nb=t&31;  kb=t>>5; }
    const int n0=nb*32, k0=kb*32;
    #pragma unroll
    for (int i=0;i<32;i+=8)
      tl[y+i][x] = W[(size_t)(k0+y+i)*N + n0+x];
    __syncthreads();
    #pragma unroll
    for (int i=0;i<32;i+=8)
      dst[(size_t)(n0+y+i)*K + k0+x] = __float2bfloat16(tl[x][y+i]);
  } else {
    for (int i=tid; i<3072; i+=256) bqkv[i] = pa.b[i>>10][i&1023];
  }
}

// ---------------- V transpose: qkv v-slice -> vT[bh][d][s] ----------------
__global__ __launch_bounds__(256) void v_transpose(
    const bf16* __restrict__ qkv, bf16* __restrict__ vT)
{
  __shared__ u16 tile[64*65];   // pitch 65 (odd) spreads banks for the column gather
  const int bh = blockIdx.y, b = bh>>4, h = bh&15;
  const int s0 = blockIdx.x*64;
  const int tid = threadIdx.x;
  const bf16* src = qkv + (size_t)(b*S_ + s0)*3072 + 2048 + h*64;
  #pragma unroll
  for (int i=0;i<2;i++){
    int idx = i*256 + tid;
    int r = idx>>3, sg = idx&7;
    uint4 v = *reinterpret_cast<const uint4*>(src + (size_t)r*3072 + sg*8);
    const u16* e = (const u16*)&v;
    #pragma unroll
    for (int j=0;j<8;j++) tile[r*65 + sg*8 + j] = e[j];
  }
  __syncthreads();
  bf16* dst = vT + (size_t)bh*64*S_ + s0;
  #pragma unroll
  for (int i=0;i<2;i++){
    int idx = i*256 + tid;
    int d = idx>>3, sg = idx&7;
    u16 tmp[8];
    #pragma unroll
    for (int j=0;j<8;j++) tmp[j] = tile[(sg*8+j)*65 + d];
    *reinterpret_cast<uint4*>(dst + (size_t)d*S_ + sg*8) = *reinterpret_cast<uint4*>(tmp);
  }
}

// ---------------- layernorm (torch-faithful: ddof=1, eps added to std) ----------------
__device__ __forceinline__ float block_reduce_256(float v, float* sbuf){
  #pragma unroll
  for (int o=32;o>0;o>>=1) v += __shfl_down(v, o);
  int wave = threadIdx.x>>6;
  if ((threadIdx.x&63)==0) sbuf[wave] = v;
  __syncthreads();
  float r = sbuf[0]+sbuf[1]+sbuf[2]+sbuf[3];
  __syncthreads();
  return r;
}

__global__ __launch_bounds__(256) void ln_fwd(
    const float* __restrict__ x, const float* __restrict__ alpha,
    const float* __restrict__ beta, bf16* __restrict__ out)
{
  __shared__ float sbuf[4];
  int row = blockIdx.x, tid = threadIdx.x;
  const float4* xr = reinterpret_cast<const float4*>(x + (size_t)row*D_);
  float4 v = xr[tid];
  float sum = block_reduce_256(v.x+v.y+v.z+v.w, sbuf);
  float mean = sum * (1.0f/1024.0f);
  float dx0=v.x-mean, dx1=v.y-mean, dx2=v.z-mean, dx3=v.w-mean;
  float ssq = block_reduce_256(dx0*dx0+dx1*dx1+dx2*dx2+dx3*dx3, sbuf);
  float std_ = sqrtf(ssq * (1.0f/1023.0f));        // ddof=1
  float inv = 1.0f/(std_ + 1e-6f);                 // eps added to std
  const float4* ar = reinterpret_cast<const float4*>(alpha);
  const float4* br = reinterpret_cast<const float4*>(beta);
  float4 a = ar[tid], bb = br[tid];
  unsigned* o = reinterpret_cast<unsigned*>(out + (size_t)row*D_);
  o[tid*2+0] = pkbf(a.x*dx0*inv + bb.x, a.y*dx1*inv + bb.y);
  o[tid*2+1] = pkbf(a.z*dx2*inv + bb.z, a.w*dx3*inv + bb.w);
}

// ---------------- GEMM: 512 threads, 128x128 tile, 8 waves of 64x32 ----------------
// (kept for N=1024 GEMMs: Wo-proj and FFN2, where a 256^2 grid would idle half the CUs)
// C[M,N] = A[M,K]_bf16 * BT[N,K]^T + bias; N must be a multiple of 128.
// EPI: 0=bf16, 1=bf16+ReLU, 2=f32+res, 3=bf16 with cols<1024 scaled by QSCALE (QKV)
template<int EPI>
__global__ __launch_bounds__(512) void gemm_bt(
    const bf16* __restrict__ A, const bf16* __restrict__ BT,
    const float* __restrict__ bias, const float* __restrict__ res,
    void* __restrict__ out, int M, int N, int K)
{
  __shared__ __align__(16) u16 As[128*32];
  __shared__ __align__(16) u16 Bs[128*32];
  const int tid = threadIdx.x;
  const int m0 = blockIdx.x*128, n0 = blockIdx.y*128;
  const int wave = tid>>6, lane = tid&63;
  const int wm = (wave>>2)*64, wn = (wave&3)*32;
  const int lrow = lane&15, quad = lane>>4;
  const int srow = wave*16 + (lane>>2);
  const int sseg = lane&3;
  const bf16* apg = A  + (size_t)(m0+srow)*K + sseg*8;
  const bf16* bpg = BT + (size_t)(n0+srow)*K + sseg*8;
  u16* asd = &As[wave*512];
  u16* bsd = &Bs[wave*512];

  f32x4 acc[4][2];
  #pragma unroll
  for (int i=0;i<4;i++)
    #pragma unroll
    for (int j=0;j<2;j++) acc[i][j] = (f32x4){0.f,0.f,0.f,0.f};

  for (int k0=0; k0<K; k0+=32) {
    gll16(apg + k0, asd);
    gll16(bpg + k0, bsd);
    __syncthreads();
    bf16x8 a[4], b[2];
    #pragma unroll
    for (int t=0;t<4;t++)
      a[t] = *reinterpret_cast<const bf16x8*>(&As[(wm + t*16 + lrow)*32 + quad*8]);
    #pragma unroll
    for (int t=0;t<2;t++)
      b[t] = *reinterpret_cast<const bf16x8*>(&Bs[(wn + t*16 + lrow)*32 + quad*8]);
    #pragma unroll
    for (int mt=0;mt<4;mt++)
      #pragma unroll
      for (int nt=0;nt<2;nt++)
        acc[mt][nt] = __builtin_amdgcn_mfma_f32_16x16x32_bf16(a[mt], b[nt], acc[mt][nt], 0,0,0);
    __syncthreads();
  }

  #pragma unroll
  for (int mt=0;mt<4;mt++){
    #pragma unroll
    for (int nt=0;nt<2;nt++){
      int col = n0 + wn + nt*16 + lrow;
      float bv = bias[col];
      float sc = (EPI == 3 && col < 1024) ? QSCALE : 1.0f;
      #pragma unroll
      for (int r=0;r<4;r++){
        int row = m0 + wm + mt*16 + quad*4 + r;
        size_t idx = (size_t)row*N + col;
        float val = acc[mt][nt][r] + bv;
        if (EPI == 1) val = fmaxf(val, 0.0f);
        if (EPI == 3) val *= sc;
        if (EPI == 2) {
          ((float*)out)[idx] = val + res[idx];
        } else {
          ((u16*)out)[idx] = bfrnd(val);
        }
      }
    }
  }
}

// ---------------- GEMM 256x256, BK=64, 8-phase pipelined (m201-style template) ----------------
// 8 waves (2M x 4N), per-wave 128x64 output. LDS 128 KiB dynamic:
//   [dbuf][A/B][half][128*64] bf16; A-half h = tile rows h*128..h*128+127, B mirrors with BT rows.
// T2 swizzle: physical 16B chunk = logical chunk ^ (row&7) (involution); staging pre-swizzles the
// per-lane GLOBAL source (global_load_lds writes linearly), reads apply the same XOR.
// Phases per K-tile: (rowhalf, kstep) = (0,0),(1,0),(0,1),(1,1); B frags for BOTH ksteps read at P1.
//   => B-halves last read at P1, A-halves at P4. Stagger (race-free, counted vmcnt):
//   P1: stage A0(t+1)->other buf   (A region of other buf fully read during t-1)
//   P2: stage A1(t+1)->other buf
//   P3: stage B0(t+2)->current buf (B region of current buf fully read at t P1)
//   P4: stage B1(t+2)->current buf; s_waitcnt vmcnt(4)  [leaves exactly B(t+2) in flight]
// vmcnt(4) guarantees A(t+1) (issued P1/P2) and B(t+1) (issued last tile) landed before t+1 P1.
#define LA256(bu,hf) (lds + (((bu)*2+0)*2+(hf))*8192)
#define LB256(bu,hf) (lds + (((bu)*2+1)*2+(hf))*8192)

__device__ __forceinline__ bf16x8 ldfrag(const u16* base, int row, int chunk){
  int pc = chunk ^ (row & 7);                       // T2 swizzle on read
  return *reinterpret_cast<const bf16x8*>(base + row*64 + pc*8);
}

__device__ __forceinline__ void stage_half256(const bf16* __restrict__ src, int K,
                                              u16* lbase, int wave, int lane){
  #pragma unroll
  for (int i=0;i<2;i++){
    int q = i*512 + wave*64 + lane;                 // physical 16B chunk index
    int row = q>>3;
    int seg = (q&7) ^ (row&7);                      // inverse swizzle on global source
    gll16(src + (size_t)row*K + seg*8, lbase + (i*512 + wave*64)*8);
  }
}

template<int RH, int KS, bool RB, typename STG, typename TAIL>
__device__ __forceinline__ void gphase(const u16* pa, const u16* pb, int bcol,
    int lr, int quad, bf16x8 (&b)[4][2], f32x4 (&acc)[8][4], STG stg, TAIL tail)
{
  bf16x8 a_[4];
  #pragma unroll
  for (int ar=0; ar<4; ar++)
    a_[ar] = ldfrag(pa, RH*64 + ar*16 + lr, KS*4 + quad);
  if constexpr (RB){
    #pragma unroll
    for (int cb=0; cb<4; cb++){
      b[cb][0] = ldfrag(pb, bcol + cb*16 + lr, quad);
      b[cb][1] = ldfrag(pb, bcol + cb*16 + lr, 4 + quad);
    }
  }
  stg();
  __builtin_amdgcn_s_barrier();
  asm volatile("s_waitcnt lgkmcnt(0)" ::: "memory");
  __builtin_amdgcn_sched_barrier(0);                // rule #18: keep MFMAs below the wait
  __builtin_amdgcn_s_setprio(1);
  #pragma unroll
  for (int ar=0; ar<4; ar++)
    #pragma unroll
    for (int cb=0; cb<4; cb++)
      acc[RH*4+ar][cb] = __builtin_amdgcn_mfma_f32_16x16x32_bf16(a_[ar], b[cb][KS], acc[RH*4+ar][cb], 0,0,0);
  __builtin_amdgcn_s_setprio(0);
  tail();
  __builtin_amdgcn_s_barrier();
}

// EPI: 1=bf16+ReLU (FFN1), 3=bf16 with cols<1024 scaled by QSCALE (QKV). M fixed = MROWS.
template<int EPI>
__global__ __launch_bounds__(512,2) void gemm256(
    const bf16* __restrict__ A, const bf16* __restrict__ BT,
    const float* __restrict__ bias, bf16* __restrict__ out, int N, int K)
{
  extern __shared__ __align__(16) u16 lds[];        // 131072 B
  const int tid = threadIdx.x, wave = tid>>6, lane = tid&63;
  const int wr = wave>>2, wc = wave&3;              // 2M x 4N wave grid
  const int lr = lane&15, quad = lane>>4;
  // T1: XCD-aware swizzle (both grids have nwg % 8 == 0)
  const int gx = gridDim.x;
  const int nwg = gx*gridDim.y;
  int flat = blockIdx.y*gx + blockIdx.x;
  int cpx = nwg>>3;
  int swz = (flat&7)*cpx + (flat>>3);
  const int m0 = (swz % gx)*256, n0 = (swz / gx)*256;
  const int T = K>>6;

  const bf16* Ag = A  + (size_t)m0*K;
  const bf16* Bg = BT + (size_t)n0*K;
  const int bcol = (wc&1)*64;

  f32x4 acc[8][4];
  #pragma unroll
  for (int i=0;i<8;i++)
    #pragma unroll
    for (int j=0;j<4;j++) acc[i][j] = (f32x4){0.f,0.f,0.f,0.f};

  // prologue: tile0 (4 halves) + B halves of tile1; allow B(1) in flight
  stage_half256(Ag,                       K, LA256(0,0), wave, lane);
  stage_half256(Ag + (size_t)128*K,       K, LA256(0,1), wave, lane);
  stage_half256(Bg,                       K, LB256(0,0), wave, lane);
  stage_half256(Bg + (size_t)128*K,       K, LB256(0,1), wave, lane);
  stage_half256(Bg + 64,                  K, LB256(1,0), wave, lane);
  stage_half256(Bg + (size_t)128*K + 64,  K, LB256(1,1), wave, lane);
  asm volatile("s_waitcnt vmcnt(4)" ::: "memory");
  __builtin_amdgcn_s_barrier();

  for (int t=0; t<T; ++t){
    const int bu = t&1, nbu = bu^1;
    const u16* pa = LA256(bu, wr);
    const u16* pb = LB256(bu, wc>>1);
    const size_t ktA = (size_t)((t+1 < T) ? t+1 : T-1)*64;   // clamp keeps vmcnt counts uniform
    const size_t ktB = (size_t)((t+2 < T) ? t+2 : T-1)*64;
    bf16x8 b[4][2];
    gphase<0,0,true >(pa, pb, bcol, lr, quad, b, acc,
        [&]{ stage_half256(Ag + ktA,                 K, LA256(nbu,0), wave, lane); }, [&]{});
    gphase<1,0,false>(pa, pb, bcol, lr, quad, b, acc,
        [&]{ stage_half256(Ag + (size_t)128*K + ktA, K, LA256(nbu,1), wave, lane); }, [&]{});
    gphase<0,1,false>(pa, pb, bcol, lr, quad, b, acc,
        [&]{ stage_half256(Bg + ktB,                 K, LB256(bu,0),  wave, lane); }, [&]{});
    gphase<1,1,false>(pa, pb, bcol, lr, quad, b, acc,
        [&]{ stage_half256(Bg + (size_t)128*K + ktB, K, LB256(bu,1),  wave, lane); },
        [&]{ asm volatile("s_waitcnt vmcnt(4)" ::: "memory"); });
  }

  // epilogue
  #pragma unroll
  for (int mi=0; mi<8; mi++){
    const int row0 = m0 + wr*128 + (mi>>2)*64 + (mi&3)*16 + quad*4;
    #pragma unroll
    for (int cb=0; cb<4; cb++){
      const int col = n0 + wc*64 + cb*16 + lr;
      float bv = bias[col];
      float sc = (EPI==3 && col < 1024) ? QSCALE : 1.0f;
      #pragma unroll
      for (int r=0; r<4; r++){
        float val = acc[mi][cb][r] + bv;
        if (EPI == 1) val = fmaxf(val, 0.0f);
        if (EPI == 3) val *= sc;
        ((u16*)out)[(size_t)(row0+r)*N + col] = bfrnd(val);
      }
    }
  }
}

// ---------------- MFMA flash attention: S^T trick, QT=256, 8 waves ----------------
#define KP 72   // LDS pitch: 144B rows, 16B-aligned for b128

__global__ __launch_bounds__(512) void flash_attn_mfma(
    const bf16* __restrict__ qkv, const bf16* __restrict__ vT,
    const int* __restrict__ mask, bf16* __restrict__ ctx)
{
  __shared__ __align__(16) u16 Ks[64*KP];       // K[key][d]
  __shared__ __align__(16) u16 Vt[64*KP];       // V^T[d][key]
  __shared__ __align__(16) float Mb[64];        // mask bias (slow path only)

  const int b = blockIdx.z, h = blockIdx.y, qt = blockIdx.x;
  const int tid = threadIdx.x, wave = tid>>6, lane = tid&63;
  const int lr = lane&15, quad = lane>>4;
  const int qbase = qt*256 + wave*32;           // 32 q-rows per wave (2 q-sets of 16)

  const bf16* base = qkv + (size_t)b*S_*3072 + h*64;
  const bf16* vtb  = vT + (size_t)(b*H_+h)*64*S_;
  const int*  mrow = mask + b*S_;

  bf16x8 qf[2][2];
  #pragma unroll
  for (int c=0;c<2;c++){
    const bf16* qp = base + (size_t)(qbase + c*16 + lr)*3072 + quad*8;
    qf[c][0] = *reinterpret_cast<const bf16x8*>(qp);
    qf[c][1] = *reinterpret_cast<const bf16x8*>(qp + 32);
  }

  const bf16x4 ones4 = {(short)0x3F80,(short)0x3F80,(short)0x3F80,(short)0x3F80};

  f32x4 actx[2][4];                              // [c][dt] : ctx^T[d=dt*16+quad*4+r][q=c*16+lr]
  f32x4 acc_l[2];                                // l per q (rows identical)
  #pragma unroll
  for (int c=0;c<2;c++){
    #pragma unroll
    for (int dt=0;dt<4;dt++) actx[c][dt] = (f32x4){0.f,0.f,0.f,0.f};
    acc_l[c] = (f32x4){0.f,0.f,0.f,0.f};
  }

  const int sr = tid>>3, sg = tid&7;

  for (int kt=0; kt<S_; kt+=64){
    *reinterpret_cast<uint4*>(&Ks[sr*KP + sg*8]) =
      *reinterpret_cast<const uint4*>(base + 1024 + (size_t)(kt+sr)*3072 + sg*8);
    *reinterpret_cast<uint4*>(&Vt[sr*KP + sg*8]) =
      *reinterpret_cast<const uint4*>(vtb + (size_t)sr*S_ + kt + sg*8);
    if (tid < 64) Mb[tid] = (mrow[kt+tid]==0) ? -2e9f : 0.0f;
    unsigned long long bal = __ballot(mrow[kt + lane] == 0);
    __syncthreads();

    bf16x4 pk[2][4];                             // [c][nt] : keys nt*16+quad*4+j, q=c*16+lr
    if (bal == 0ULL) {
      #pragma unroll
      for (int nt=0;nt<4;nt++){
        bf16x8 kf0 = *reinterpret_cast<const bf16x8*>(&Ks[(nt*16+lr)*KP + quad*8]);
        bf16x8 kf1 = *reinterpret_cast<const bf16x8*>(&Ks[(nt*16+lr)*KP + 32 + quad*8]);
        #pragma unroll
        for (int c=0;c<2;c++){
          f32x4 a = (f32x4){0.f,0.f,0.f,0.f};
          a = __builtin_amdgcn_mfma_f32_16x16x32_bf16(kf0, qf[c][0], a, 0,0,0);
          a = __builtin_amdgcn_mfma_f32_16x16x32_bf16(kf1, qf[c][1], a, 0,0,0);
          uint2 w;
          w.x = pkbf(__builtin_amdgcn_exp2f(a[0]), __builtin_amdgcn_exp2f(a[1]));
          w.y = pkbf(__builtin_amdgcn_exp2f(a[2]), __builtin_amdgcn_exp2f(a[3]));
          union{uint2 u; bf16x4 v;} cvt; cvt.u = w;
          pk[c][nt] = cvt.v;
        }
      }
    } else {
      #pragma unroll
      for (int nt=0;nt<4;nt++){
        bf16x8 kf0 = *reinterpret_cast<const bf16x8*>(&Ks[(nt*16+lr)*KP + quad*8]);
        bf16x8 kf1 = *reinterpret_cast<const bf16x8*>(&Ks[(nt*16+lr)*KP + 32 + quad*8]);
        float4 mb = *reinterpret_cast<const float4*>(&Mb[nt*16 + quad*4]);
        #pragma unroll
        for (int c=0;c<2;c++){
          f32x4 a = (f32x4){0.f,0.f,0.f,0.f};
          a = __builtin_amdgcn_mfma_f32_16x16x32_bf16(kf0, qf[c][0], a, 0,0,0);
          a = __builtin_amdgcn_mfma_f32_16x16x32_bf16(kf1, qf[c][1], a, 0,0,0);
          uint2 w;
          w.x = pkbf(__builtin_amdgcn_exp2f(a[0]+mb.x), __builtin_amdgcn_exp2f(a[1]+mb.y));
          w.y = pkbf(__builtin_amdgcn_exp2f(a[2]+mb.z), __builtin_amdgcn_exp2f(a[3]+mb.w));
          union{uint2 u; bf16x4 v;} cvt; cvt.u = w;
          pk[c][nt] = cvt.v;
        }
      }
    }

    #pragma unroll
    for (int dt=0;dt<4;dt++){
      #pragma unroll
      for (int kc=0;kc<4;kc++){
        bf16x4 vf = *reinterpret_cast<const bf16x4*>(&Vt[(dt*16+lr)*KP + kc*16 + quad*4]);
        #pragma unroll
        for (int c=0;c<2;c++)
          actx[c][dt] = __builtin_amdgcn_mfma_f32_16x16x16bf16_1k(vf, pk[c][kc], actx[c][dt], 0,0,0);
      }
    }
    #pragma unroll
    for (int kc=0;kc<4;kc++)
      #pragma unroll
      for (int c=0;c<2;c++)
        acc_l[c] = __builtin_amdgcn_mfma_f32_16x16x16bf16_1k(ones4, pk[c][kc], acc_l[c], 0,0,0);
    __syncthreads();
  }

  #pragma unroll
  for (int c=0;c<2;c++){
    float inv = 1.0f/acc_l[c][0];
    int q = qbase + c*16 + lr;
    bf16* op = ctx + (size_t)(b*S_+q)*D_ + h*64 + quad*4;
    #pragma unroll
    for (int dt=0;dt<4;dt++){
      uint2 o;
      o.x = pkbf(actx[c][dt][0]*inv, actx[c][dt][1]*inv);
      o.y = pkbf(actx[c][dt][2]*inv, actx[c][dt][3]*inv);
      *reinterpret_cast<uint2*>(op + dt*16) = o;
    }
  }
}

// ---------------- launch ----------------
extern "C" void kernel_launch(void* const* d_in, const int* in_sizes, int n_in,
                              void* d_out, int out_size, void* d_ws, size_t ws_size,
                              hipStream_t stream) {
  const float* x    = (const float*)d_in[0];
  const int*   mask = (const int*)  d_in[1];
  const float* wq   = (const float*)d_in[2];
  const float* bq   = (const float*)d_in[3];
  const float* wk   = (const float*)d_in[4];
  const float* bk   = (const float*)d_in[5];
  const float* wv   = (const float*)d_in[6];
  const float* bv   = (const float*)d_in[7];
  const float* wo   = (const float*)d_in[8];
  const float* bo   = (const float*)d_in[9];
  const float* w1   = (const float*)d_in[10];
  const float* b1   = (const float*)d_in[11];
  const float* w2   = (const float*)d_in[12];
  const float* b2   = (const float*)d_in[13];
  const float* ln1a = (const float*)d_in[14];
  const float* ln1b = (const float*)d_in[15];
  const float* ln2a = (const float*)d_in[16];
  const float* ln2b = (const float*)d_in[17];

  char* ws = (char*)d_ws;
  bf16*  wqkvT = (bf16*) (ws + 0);                 //  6 MB [3072][1024]
  bf16*  woT   = (bf16*) (ws + 6291456);           //  2 MB [1024][1024]
  bf16*  w1T   = (bf16*) (ws + 8388608);           //  8 MB [4096][1024]
  bf16*  w2T   = (bf16*) (ws + 16777216);          //  8 MB [1024][4096]
  float* bqkv  = (float*)(ws + 25165824);          // 12 KB [3072]
  bf16*  xn    = (bf16*) (ws + 25178112);          // 16 MB [8192][1024] (dead after QKV gemm)
  bf16*  vT    = (bf16*) (ws + 25178112);          // 16 MB [64][64][2048], reuses xn slot
  bf16*  qkv   = (bf16*) (ws + 41955328);          // 48 MB [8192][3072]
  bf16*  ctx   = (bf16*) (ws + 92286976);          // 16 MB [8192][1024]
  bf16*  hn    = (bf16*) (ws + 109064192);         // 16 MB [8192][1024]
  bf16*  act   = (bf16*) (ws + 25178112);          // 64 MB [8192][4096], aliases vT+qkv (dead by then)

  // one-time: allow 128 KiB dynamic LDS for the 8-phase GEMMs; fall back to the
  // 128^2 kernels if the attribute isn't supported (diagnostic-safe, no regression).
  static bool newgemm_ok = [](){
    hipError_t e1 = hipFuncSetAttribute((const void*)gemm256<3>,
        hipFuncAttributeMaxDynamicSharedMemorySize, 131072);
    hipError_t e2 = hipFuncSetAttribute((const void*)gemm256<1>,
        hipFuncAttributeMaxDynamicSharedMemorySize, 131072);
    return e1 == hipSuccess && e2 == hipSuccess;
  }();

  PrepArgs pa;
  pa.w[0]=wq; pa.w[1]=wk; pa.w[2]=wv; pa.w[3]=wo; pa.w[4]=w1; pa.w[5]=w2;
  pa.b[0]=bq; pa.b[1]=bk; pa.b[2]=bv;
  prep<<<12289,256,0,stream>>>(pa, wqkvT, w1T, w2T, bqkv);

  // LN1 -> xn
  ln_fwd<<<8192,256,0,stream>>>(x, ln1a, ln1b, xn);
  // QKV projection: [8192,3072]; q-slice scaled by QSCALE in epilogue (EPI=3)
  if (newgemm_ok)
    gemm256<3><<<dim3(32,12),512,131072,stream>>>(xn, wqkvT, bqkv, qkv, 3072, 1024);
  else
    gemm_bt<3><<<dim3(64,24),512,0,stream>>>(xn, wqkvT, bqkv, nullptr, qkv, MROWS,3072,1024);
  // V -> vT[bh][d][s]
  v_transpose<<<dim3(32,64),256,0,stream>>>(qkv, vT);
  // attention -> ctx (MFMA flash, QT=256 per block, 8 waves)
  flash_attn_mfma<<<dim3(S_/256,H_,B_),512,0,stream>>>(qkv, vT, mask, ctx);
  // out projection + residual(x) -> h (stored in d_out, f32)
  gemm_bt<2><<<dim3(64,8),512,0,stream>>>(ctx, woT, bo, x, d_out, MROWS,1024,1024);
  // LN2 -> hn
  ln_fwd<<<8192,256,0,stream>>>((const float*)d_out, ln2a, ln2b, hn);
  // FFN1 + ReLU -> act
  if (newgemm_ok)
    gemm256<1><<<dim3(32,16),512,131072,stream>>>(hn, w1T, b1, act, F_, 1024);
  else
    gemm_bt<1><<<dim3(64,32),512,0,stream>>>(hn, w1T, b1, nullptr, act, MROWS,F_,1024);
  // FFN2 + residual(h) -> d_out
  gemm_bt<2><<<dim3(64,8),512,0,stream>>>(act, w2T, b2, (const float*)d_out, d_out, MROWS,1024,F_);
}

// Round 4
// 527.119 us; speedup vs baseline: 1.0415x; 1.0378x over previous
//
#include <hip/hip_runtime.h>
#include <hip/hip_bf16.h>

typedef __attribute__((ext_vector_type(8))) short bf16x8;
typedef __attribute__((ext_vector_type(4))) short bf16x4;
typedef __attribute__((ext_vector_type(4))) float f32x4;
typedef __hip_bfloat16 bf16;
typedef unsigned short u16;

#define B_ 4
#define S_ 2048
#define D_ 1024
#define F_ 4096
#define H_ 16
#define MROWS 8192   // B_*S_
// 1/sqrt(dk) * log2(e), folded into the q-slice of the QKV GEMM epilogue
#define QSCALE 0.18033688011116012f

// ---------------- helpers ----------------
// pack 2 f32 -> 2 bf16 (round-half-up): 2 adds + 1 v_perm
__device__ __forceinline__ unsigned pkbf(float lo, float hi){
  union{float f; unsigned u;} a, b; a.f = lo; b.f = hi;
  return __builtin_amdgcn_perm(b.u + 0x8000u, a.u + 0x8000u, 0x07060302);
}
// single f32 -> bf16 bits (round-half-up): 2 VALU
__device__ __forceinline__ u16 bfrnd(float f){
  union{float ff; unsigned u;} c; c.ff = f;
  return (u16)((c.u + 0x8000u) >> 16);
}
// async global->LDS, 16B per lane; LDS dest = wave-uniform base + lane*16
__device__ __forceinline__ void gll16(const bf16* gp, u16* lp){
  __builtin_amdgcn_global_load_lds(
      (const __attribute__((address_space(1))) void*)gp,
      (__attribute__((address_space(3))) void*)lp, 16, 0, 0);
}

// ---------------- fused prep: 6 weight transposes + bias concat, ONE launch ----------------
// transpose semantics: W[K][N] f32 -> WT[N][K] bf16
struct PrepArgs { const float* w[6]; const float* b[3]; };
__global__ __launch_bounds__(256) void prep(
    PrepArgs pa, bf16* __restrict__ wqkvoT, bf16* __restrict__ w1T,
    bf16* __restrict__ w2T, float* __restrict__ bqkv)
{
  __shared__ float tl[32][33];
  const int bid = blockIdx.x, tid = threadIdx.x;
  const int x = tid&31, y = tid>>5;
  if (bid < 12288) {
    const float* W; bf16* dst; int K, N, nb, kb;
    if (bid < 4096)      { int wi=bid>>10, t=bid&1023; W=pa.w[wi]; dst=wqkvoT+(size_t)wi*1048576; K=1024; N=1024; nb=t&31;  kb=t>>5; }
    else if (bid < 8192) { int t=bid-4096;             W=pa.w[4];  dst=w1T;  K=1024; N=4096; nb=t&127; kb=t>>7; }
    else                 { int t=bid-8192;             W=pa.w[5];  dst=w2T;  K=4096; N=1024; nb=t&31;  kb=t>>5; }
    const int n0=nb*32, k0=kb*32;
    #pragma unroll
    for (int i=0;i<32;i+=8)
      tl[y+i][x] = W[(size_t)(k0+y+i)*N + n0+x];
    __syncthreads();
    #pragma unroll
    for (int i=0;i<32;i+=8)
      dst[(size_t)(n0+y+i)*K + k0+x] = __float2bfloat16(tl[x][y+i]);
  } else {
    for (int i=tid; i<3072; i+=256) bqkv[i] = pa.b[i>>10][i&1023];
  }
}

// ---------------- V transpose: qkv v-slice -> vT[bh][d][s] ----------------
__global__ __launch_bounds__(256) void v_transpose(
    const bf16* __restrict__ qkv, bf16* __restrict__ vT)
{
  __shared__ u16 tile[64*65];   // pitch 65 (odd) spreads banks for the column gather
  const int bh = blockIdx.y, b = bh>>4, h = bh&15;
  const int s0 = blockIdx.x*64;
  const int tid = threadIdx.x;
  const bf16* src = qkv + (size_t)(b*S_ + s0)*3072 + 2048 + h*64;
  #pragma unroll
  for (int i=0;i<2;i++){
    int idx = i*256 + tid;
    int r = idx>>3, sg = idx&7;
    uint4 v = *reinterpret_cast<const uint4*>(src + (size_t)r*3072 + sg*8);
    const u16* e = (const u16*)&v;
    #pragma unroll
    for (int j=0;j<8;j++) tile[r*65 + sg*8 + j] = e[j];
  }
  __syncthreads();
  bf16* dst = vT + (size_t)bh*64*S_ + s0;
  #pragma unroll
  for (int i=0;i<2;i++){
    int idx = i*256 + tid;
    int d = idx>>3, sg = idx&7;
    u16 tmp[8];
    #pragma unroll
    for (int j=0;j<8;j++) tmp[j] = tile[(sg*8+j)*65 + d];
    *reinterpret_cast<uint4*>(dst + (size_t)d*S_ + sg*8) = *reinterpret_cast<uint4*>(tmp);
  }
}

// ---------------- layernorm (torch-faithful: ddof=1, eps added to std) ----------------
__device__ __forceinline__ float block_reduce_256(float v, float* sbuf){
  #pragma unroll
  for (int o=32;o>0;o>>=1) v += __shfl_down(v, o);
  int wave = threadIdx.x>>6;
  if ((threadIdx.x&63)==0) sbuf[wave] = v;
  __syncthreads();
  float r = sbuf[0]+sbuf[1]+sbuf[2]+sbuf[3];
  __syncthreads();
  return r;
}

__global__ __launch_bounds__(256) void ln_fwd(
    const float* __restrict__ x, const float* __restrict__ alpha,
    const float* __restrict__ beta, bf16* __restrict__ out)
{
  __shared__ float sbuf[4];
  int row = blockIdx.x, tid = threadIdx.x;
  const float4* xr = reinterpret_cast<const float4*>(x + (size_t)row*D_);
  float4 v = xr[tid];
  float sum = block_reduce_256(v.x+v.y+v.z+v.w, sbuf);
  float mean = sum * (1.0f/1024.0f);
  float dx0=v.x-mean, dx1=v.y-mean, dx2=v.z-mean, dx3=v.w-mean;
  float ssq = block_reduce_256(dx0*dx0+dx1*dx1+dx2*dx2+dx3*dx3, sbuf);
  float std_ = sqrtf(ssq * (1.0f/1023.0f));        // ddof=1
  float inv = 1.0f/(std_ + 1e-6f);                 // eps added to std
  const float4* ar = reinterpret_cast<const float4*>(alpha);
  const float4* br = reinterpret_cast<const float4*>(beta);
  float4 a = ar[tid], bb = br[tid];
  unsigned* o = reinterpret_cast<unsigned*>(out + (size_t)row*D_);
  o[tid*2+0] = pkbf(a.x*dx0*inv + bb.x, a.y*dx1*inv + bb.y);
  o[tid*2+1] = pkbf(a.z*dx2*inv + bb.z, a.w*dx3*inv + bb.w);
}

// ---------------- GEMM: 512 threads, 128x128 tile, 8 waves of 64x32 ----------------
// (kept for N=1024 GEMMs: Wo-proj and FFN2, where a 256^2 grid would idle half the CUs)
// C[M,N] = A[M,K]_bf16 * BT[N,K]^T + bias; N must be a multiple of 128.
// EPI: 0=bf16, 1=bf16+ReLU, 2=f32+res, 3=bf16 with cols<1024 scaled by QSCALE (QKV)
template<int EPI>
__global__ __launch_bounds__(512) void gemm_bt(
    const bf16* __restrict__ A, const bf16* __restrict__ BT,
    const float* __restrict__ bias, const float* __restrict__ res,
    void* __restrict__ out, int M, int N, int K)
{
  __shared__ __align__(16) u16 As[128*32];
  __shared__ __align__(16) u16 Bs[128*32];
  const int tid = threadIdx.x;
  const int m0 = blockIdx.x*128, n0 = blockIdx.y*128;
  const int wave = tid>>6, lane = tid&63;
  const int wm = (wave>>2)*64, wn = (wave&3)*32;
  const int lrow = lane&15, quad = lane>>4;
  const int srow = wave*16 + (lane>>2);
  const int sseg = lane&3;
  const bf16* apg = A  + (size_t)(m0+srow)*K + sseg*8;
  const bf16* bpg = BT + (size_t)(n0+srow)*K + sseg*8;
  u16* asd = &As[wave*512];
  u16* bsd = &Bs[wave*512];

  f32x4 acc[4][2];
  #pragma unroll
  for (int i=0;i<4;i++)
    #pragma unroll
    for (int j=0;j<2;j++) acc[i][j] = (f32x4){0.f,0.f,0.f,0.f};

  for (int k0=0; k0<K; k0+=32) {
    gll16(apg + k0, asd);
    gll16(bpg + k0, bsd);
    __syncthreads();
    bf16x8 a[4], b[2];
    #pragma unroll
    for (int t=0;t<4;t++)
      a[t] = *reinterpret_cast<const bf16x8*>(&As[(wm + t*16 + lrow)*32 + quad*8]);
    #pragma unroll
    for (int t=0;t<2;t++)
      b[t] = *reinterpret_cast<const bf16x8*>(&Bs[(wn + t*16 + lrow)*32 + quad*8]);
    #pragma unroll
    for (int mt=0;mt<4;mt++)
      #pragma unroll
      for (int nt=0;nt<2;nt++)
        acc[mt][nt] = __builtin_amdgcn_mfma_f32_16x16x32_bf16(a[mt], b[nt], acc[mt][nt], 0,0,0);
    __syncthreads();
  }

  #pragma unroll
  for (int mt=0;mt<4;mt++){
    #pragma unroll
    for (int nt=0;nt<2;nt++){
      int col = n0 + wn + nt*16 + lrow;
      float bv = bias[col];
      float sc = (EPI == 3 && col < 1024) ? QSCALE : 1.0f;
      #pragma unroll
      for (int r=0;r<4;r++){
        int row = m0 + wm + mt*16 + quad*4 + r;
        size_t idx = (size_t)row*N + col;
        float val = acc[mt][nt][r] + bv;
        if (EPI == 1) val = fmaxf(val, 0.0f);
        if (EPI == 3) val *= sc;
        if (EPI == 2) {
          ((float*)out)[idx] = val + res[idx];
        } else {
          ((u16*)out)[idx] = bfrnd(val);
        }
      }
    }
  }
}

// ---------------- GEMM 256x256, BK=64, 8-phase pipelined (m201-style template) ----------------
// 8 waves (2M x 4N), per-wave 128x64 output. LDS 128 KiB STATIC (gfx950 allows 160 KiB;
// no hipFuncSetAttribute dependency -- the round-1 dynamic-LDS opt-in silently failed).
//   [dbuf][A/B][half][128*64] bf16; A-half h = tile rows h*128..h*128+127, B mirrors with BT rows.
// T2 swizzle: physical 16B chunk = logical chunk ^ (row&7) (involution); staging pre-swizzles the
// per-lane GLOBAL source (global_load_lds writes linearly), reads apply the same XOR.
// Phases per K-tile: (rowhalf, kstep) = (0,0),(1,0),(0,1),(1,1); B frags for BOTH ksteps read at P1.
//   => B-halves last read at P1, A-halves at P4. Stagger (race-free, counted vmcnt):
//   P1: stage A0(t+1)->other buf   (A region of other buf fully read during t-1)
//   P2: stage A1(t+1)->other buf
//   P3: stage B0(t+2)->current buf (B region of current buf fully read at t P1)
//   P4: stage B1(t+2)->current buf; s_waitcnt vmcnt(4)  [leaves exactly B(t+2) in flight]
// vmcnt(4) guarantees A(t+1) (issued P1/P2) and B(t+1) (issued last tile) landed before t+1 P1.
#define LA256(bu,hf) (lds + (((bu)*2+0)*2+(hf))*8192)
#define LB256(bu,hf) (lds + (((bu)*2+1)*2+(hf))*8192)

__device__ __forceinline__ bf16x8 ldfrag(const u16* base, int row, int chunk){
  int pc = chunk ^ (row & 7);                       // T2 swizzle on read
  return *reinterpret_cast<const bf16x8*>(base + row*64 + pc*8);
}

__device__ __forceinline__ void stage_half256(const bf16* __restrict__ src, int K,
                                              u16* lbase, int wave, int lane){
  #pragma unroll
  for (int i=0;i<2;i++){
    int q = i*512 + wave*64 + lane;                 // physical 16B chunk index
    int row = q>>3;
    int seg = (q&7) ^ (row&7);                      // inverse swizzle on global source
    gll16(src + (size_t)row*K + seg*8, lbase + (i*512 + wave*64)*8);
  }
}

template<int RH, int KS, bool RB, typename STG, typename TAIL>
__device__ __forceinline__ void gphase(const u16* pa, const u16* pb, int bcol,
    int lr, int quad, bf16x8 (&b)[4][2], f32x4 (&acc)[8][4], STG stg, TAIL tail)
{
  bf16x8 a_[4];
  #pragma unroll
  for (int ar=0; ar<4; ar++)
    a_[ar] = ldfrag(pa, RH*64 + ar*16 + lr, KS*4 + quad);
  if constexpr (RB){
    #pragma unroll
    for (int cb=0; cb<4; cb++){
      b[cb][0] = ldfrag(pb, bcol + cb*16 + lr, quad);
      b[cb][1] = ldfrag(pb, bcol + cb*16 + lr, 4 + quad);
    }
  }
  stg();
  __builtin_amdgcn_s_barrier();
  asm volatile("s_waitcnt lgkmcnt(0)" ::: "memory");
  __builtin_amdgcn_sched_barrier(0);                // rule #18: keep MFMAs below the wait
  __builtin_amdgcn_s_setprio(1);
  #pragma unroll
  for (int ar=0; ar<4; ar++)
    #pragma unroll
    for (int cb=0; cb<4; cb++)
      acc[RH*4+ar][cb] = __builtin_amdgcn_mfma_f32_16x16x32_bf16(a_[ar], b[cb][KS], acc[RH*4+ar][cb], 0,0,0);
  __builtin_amdgcn_s_setprio(0);
  tail();
  __builtin_amdgcn_s_barrier();
}

// EPI: 1=bf16+ReLU (FFN1), 3=bf16 with cols<1024 scaled by QSCALE (QKV). M fixed = MROWS.
template<int EPI>
__global__ __launch_bounds__(512) void gemm256(
    const bf16* __restrict__ A, const bf16* __restrict__ BT,
    const float* __restrict__ bias, bf16* __restrict__ out, int N, int K)
{
  __shared__ __align__(16) u16 lds[65536];          // 131072 B static (gfx950: 160 KiB LDS)
  const int tid = threadIdx.x, wave = tid>>6, lane = tid&63;
  const int wr = wave>>2, wc = wave&3;              // 2M x 4N wave grid
  const int lr = lane&15, quad = lane>>4;
  // T1: XCD-aware swizzle (both grids have nwg % 8 == 0)
  const int gx = gridDim.x;
  const int nwg = gx*gridDim.y;
  int flat = blockIdx.y*gx + blockIdx.x;
  int cpx = nwg>>3;
  int swz = (flat&7)*cpx + (flat>>3);
  const int m0 = (swz % gx)*256, n0 = (swz / gx)*256;
  const int T = K>>6;

  const bf16* Ag = A  + (size_t)m0*K;
  const bf16* Bg = BT + (size_t)n0*K;
  const int bcol = (wc&1)*64;

  f32x4 acc[8][4];
  #pragma unroll
  for (int i=0;i<8;i++)
    #pragma unroll
    for (int j=0;j<4;j++) acc[i][j] = (f32x4){0.f,0.f,0.f,0.f};

  // prologue: tile0 (4 halves) + B halves of tile1; allow B(1) in flight
  stage_half256(Ag,                       K, LA256(0,0), wave, lane);
  stage_half256(Ag + (size_t)128*K,       K, LA256(0,1), wave, lane);
  stage_half256(Bg,                       K, LB256(0,0), wave, lane);
  stage_half256(Bg + (size_t)128*K,       K, LB256(0,1), wave, lane);
  stage_half256(Bg + 64,                  K, LB256(1,0), wave, lane);
  stage_half256(Bg + (size_t)128*K + 64,  K, LB256(1,1), wave, lane);
  asm volatile("s_waitcnt vmcnt(4)" ::: "memory");
  __builtin_amdgcn_s_barrier();

  for (int t=0; t<T; ++t){
    const int bu = t&1, nbu = bu^1;
    const u16* pa = LA256(bu, wr);
    const u16* pb = LB256(bu, wc>>1);
    const size_t ktA = (size_t)((t+1 < T) ? t+1 : T-1)*64;   // clamp keeps vmcnt counts uniform
    const size_t ktB = (size_t)((t+2 < T) ? t+2 : T-1)*64;
    bf16x8 b[4][2];
    gphase<0,0,true >(pa, pb, bcol, lr, quad, b, acc,
        [&]{ stage_half256(Ag + ktA,                 K, LA256(nbu,0), wave, lane); }, [&]{});
    gphase<1,0,false>(pa, pb, bcol, lr, quad, b, acc,
        [&]{ stage_half256(Ag + (size_t)128*K + ktA, K, LA256(nbu,1), wave, lane); }, [&]{});
    gphase<0,1,false>(pa, pb, bcol, lr, quad, b, acc,
        [&]{ stage_half256(Bg + ktB,                 K, LB256(bu,0),  wave, lane); }, [&]{});
    gphase<1,1,false>(pa, pb, bcol, lr, quad, b, acc,
        [&]{ stage_half256(Bg + (size_t)128*K + ktB, K, LB256(bu,1),  wave, lane); },
        [&]{ asm volatile("s_waitcnt vmcnt(4)" ::: "memory"); });
  }

  // epilogue
  #pragma unroll
  for (int mi=0; mi<8; mi++){
    const int row0 = m0 + wr*128 + (mi>>2)*64 + (mi&3)*16 + quad*4;
    #pragma unroll
    for (int cb=0; cb<4; cb++){
      const int col = n0 + wc*64 + cb*16 + lr;
      float bv = bias[col];
      float sc = (EPI==3 && col < 1024) ? QSCALE : 1.0f;
      #pragma unroll
      for (int r=0; r<4; r++){
        float val = acc[mi][cb][r] + bv;
        if (EPI == 1) val = fmaxf(val, 0.0f);
        if (EPI == 3) val *= sc;
        ((u16*)out)[(size_t)(row0+r)*N + col] = bfrnd(val);
      }
    }
  }
}

// ---------------- MFMA flash attention: S^T trick, QT=256, 8 waves ----------------
// Vt is XOR-swizzled at 16B-chunk granularity (chunk' = chunk ^ (row&7)): the PV b64
// gather previously hit ~4-way bank conflicts (1.26e7 conflict cycles/dispatch ~= 19%
// of kernel time). Swizzled reads land 4 lanes per 2-bank slot = uniform minimum.
// Ks keeps pitch 72 (its row-dependent bank spread is already ~conflict-free).
#define KP 72   // Ks LDS pitch: 144B rows, 16B-aligned for b128

__global__ __launch_bounds__(512) void flash_attn_mfma(
    const bf16* __restrict__ qkv, const bf16* __restrict__ vT,
    const int* __restrict__ mask, bf16* __restrict__ ctx)
{
  __shared__ __align__(16) u16 Ks[64*KP];       // K[key][d]
  __shared__ __align__(16) u16 Vt[64*64];       // V^T[d][key], 16B-chunk swizzled
  __shared__ __align__(16) float Mb[64];        // mask bias (slow path only)

  const int b = blockIdx.z, h = blockIdx.y, qt = blockIdx.x;
  const int tid = threadIdx.x, wave = tid>>6, lane = tid&63;
  const int lr = lane&15, quad = lane>>4;
  const int qbase = qt*256 + wave*32;           // 32 q-rows per wave (2 q-sets of 16)

  const bf16* base = qkv + (size_t)b*S_*3072 + h*64;
  const bf16* vtb  = vT + (size_t)(b*H_+h)*64*S_;
  const int*  mrow = mask + b*S_;

  bf16x8 qf[2][2];
  #pragma unroll
  for (int c=0;c<2;c++){
    const bf16* qp = base + (size_t)(qbase + c*16 + lr)*3072 + quad*8;
    qf[c][0] = *reinterpret_cast<const bf16x8*>(qp);
    qf[c][1] = *reinterpret_cast<const bf16x8*>(qp + 32);
  }

  const bf16x4 ones4 = {(short)0x3F80,(short)0x3F80,(short)0x3F80,(short)0x3F80};

  f32x4 actx[2][4];                              // [c][dt] : ctx^T[d=dt*16+quad*4+r][q=c*16+lr]
  f32x4 acc_l[2];                                // l per q (rows identical)
  #pragma unroll
  for (int c=0;c<2;c++){
    #pragma unroll
    for (int dt=0;dt<4;dt++) actx[c][dt] = (f32x4){0.f,0.f,0.f,0.f};
    acc_l[c] = (f32x4){0.f,0.f,0.f,0.f};
  }

  const int sr = tid>>3, sg = tid&7;

  for (int kt=0; kt<S_; kt+=64){
    *reinterpret_cast<uint4*>(&Ks[sr*KP + sg*8]) =
      *reinterpret_cast<const uint4*>(base + 1024 + (size_t)(kt+sr)*3072 + sg*8);
    *reinterpret_cast<uint4*>(&Vt[sr*64 + ((sg ^ (sr&7))<<3)]) =
      *reinterpret_cast<const uint4*>(vtb + (size_t)sr*S_ + kt + sg*8);
    if (tid < 64) Mb[tid] = (mrow[kt+tid]==0) ? -2e9f : 0.0f;
    unsigned long long bal = __ballot(mrow[kt + lane] == 0);
    __syncthreads();

    bf16x4 pk[2][4];                             // [c][nt] : keys nt*16+quad*4+j, q=c*16+lr
    if (bal == 0ULL) {
      #pragma unroll
      for (int nt=0;nt<4;nt++){
        bf16x8 kf0 = *reinterpret_cast<const bf16x8*>(&Ks[(nt*16+lr)*KP + quad*8]);
        bf16x8 kf1 = *reinterpret_cast<const bf16x8*>(&Ks[(nt*16+lr)*KP + 32 + quad*8]);
        #pragma unroll
        for (int c=0;c<2;c++){
          f32x4 a = (f32x4){0.f,0.f,0.f,0.f};
          a = __builtin_amdgcn_mfma_f32_16x16x32_bf16(kf0, qf[c][0], a, 0,0,0);
          a = __builtin_amdgcn_mfma_f32_16x16x32_bf16(kf1, qf[c][1], a, 0,0,0);
          uint2 w;
          w.x = pkbf(__builtin_amdgcn_exp2f(a[0]), __builtin_amdgcn_exp2f(a[1]));
          w.y = pkbf(__builtin_amdgcn_exp2f(a[2]), __builtin_amdgcn_exp2f(a[3]));
          union{uint2 u; bf16x4 v;} cvt; cvt.u = w;
          pk[c][nt] = cvt.v;
        }
      }
    } else {
      #pragma unroll
      for (int nt=0;nt<4;nt++){
        bf16x8 kf0 = *reinterpret_cast<const bf16x8*>(&Ks[(nt*16+lr)*KP + quad*8]);
        bf16x8 kf1 = *reinterpret_cast<const bf16x8*>(&Ks[(nt*16+lr)*KP + 32 + quad*8]);
        float4 mb = *reinterpret_cast<const float4*>(&Mb[nt*16 + quad*4]);
        #pragma unroll
        for (int c=0;c<2;c++){
          f32x4 a = (f32x4){0.f,0.f,0.f,0.f};
          a = __builtin_amdgcn_mfma_f32_16x16x32_bf16(kf0, qf[c][0], a, 0,0,0);
          a = __builtin_amdgcn_mfma_f32_16x16x32_bf16(kf1, qf[c][1], a, 0,0,0);
          uint2 w;
          w.x = pkbf(__builtin_amdgcn_exp2f(a[0]+mb.x), __builtin_amdgcn_exp2f(a[1]+mb.y));
          w.y = pkbf(__builtin_amdgcn_exp2f(a[2]+mb.z), __builtin_amdgcn_exp2f(a[3]+mb.w));
          union{uint2 u; bf16x4 v;} cvt; cvt.u = w;
          pk[c][nt] = cvt.v;
        }
      }
    }

    // ---- ctx^T += V^T P^T ; l += 1^T P (both on MFMA pipe) ----
    #pragma unroll
    for (int dt=0;dt<4;dt++){
      #pragma unroll
      for (int kc=0;kc<4;kc++){
        int voff = ((((kc<<1) + (quad>>1)) ^ (lr&7))<<3) + ((quad&1)<<2);
        bf16x4 vf = *reinterpret_cast<const bf16x4*>(&Vt[(dt*16+lr)*64 + voff]);
        #pragma unroll
        for (int c=0;c<2;c++)
          actx[c][dt] = __builtin_amdgcn_mfma_f32_16x16x16bf16_1k(vf, pk[c][kc], actx[c][dt], 0,0,0);
      }
    }
    #pragma unroll
    for (int kc=0;kc<4;kc++)
      #pragma unroll
      for (int c=0;c<2;c++)
        acc_l[c] = __builtin_amdgcn_mfma_f32_16x16x16bf16_1k(ones4, pk[c][kc], acc_l[c], 0,0,0);
    __syncthreads();
  }

  #pragma unroll
  for (int c=0;c<2;c++){
    float inv = 1.0f/acc_l[c][0];
    int q = qbase + c*16 + lr;
    bf16* op = ctx + (size_t)(b*S_+q)*D_ + h*64 + quad*4;
    #pragma unroll
    for (int dt=0;dt<4;dt++){
      uint2 o;
      o.x = pkbf(actx[c][dt][0]*inv, actx[c][dt][1]*inv);
      o.y = pkbf(actx[c][dt][2]*inv, actx[c][dt][3]*inv);
      *reinterpret_cast<uint2*>(op + dt*16) = o;
    }
  }
}

// ---------------- launch ----------------
extern "C" void kernel_launch(void* const* d_in, const int* in_sizes, int n_in,
                              void* d_out, int out_size, void* d_ws, size_t ws_size,
                              hipStream_t stream) {
  const float* x    = (const float*)d_in[0];
  const int*   mask = (const int*)  d_in[1];
  const float* wq   = (const float*)d_in[2];
  const float* bq   = (const float*)d_in[3];
  const float* wk   = (const float*)d_in[4];
  const float* bk   = (const float*)d_in[5];
  const float* wv   = (const float*)d_in[6];
  const float* bv   = (const float*)d_in[7];
  const float* wo   = (const float*)d_in[8];
  const float* bo   = (const float*)d_in[9];
  const float* w1   = (const float*)d_in[10];
  const float* b1   = (const float*)d_in[11];
  const float* w2   = (const float*)d_in[12];
  const float* b2   = (const float*)d_in[13];
  const float* ln1a = (const float*)d_in[14];
  const float* ln1b = (const float*)d_in[15];
  const float* ln2a = (const float*)d_in[16];
  const float* ln2b = (const float*)d_in[17];

  char* ws = (char*)d_ws;
  bf16*  wqkvT = (bf16*) (ws + 0);                 //  6 MB [3072][1024]
  bf16*  woT   = (bf16*) (ws + 6291456);           //  2 MB [1024][1024]
  bf16*  w1T   = (bf16*) (ws + 8388608);           //  8 MB [4096][1024]
  bf16*  w2T   = (bf16*) (ws + 16777216);          //  8 MB [1024][4096]
  float* bqkv  = (float*)(ws + 25165824);          // 12 KB [3072]
  bf16*  xn    = (bf16*) (ws + 25178112);          // 16 MB [8192][1024] (dead after QKV gemm)
  bf16*  vT    = (bf16*) (ws + 25178112);          // 16 MB [64][64][2048], reuses xn slot
  bf16*  qkv   = (bf16*) (ws + 41955328);          // 48 MB [8192][3072]
  bf16*  ctx   = (bf16*) (ws + 92286976);          // 16 MB [8192][1024]
  bf16*  hn    = (bf16*) (ws + 109064192);         // 16 MB [8192][1024]
  bf16*  act   = (bf16*) (ws + 25178112);          // 64 MB [8192][4096], aliases vT+qkv (dead by then)

  PrepArgs pa;
  pa.w[0]=wq; pa.w[1]=wk; pa.w[2]=wv; pa.w[3]=wo; pa.w[4]=w1; pa.w[5]=w2;
  pa.b[0]=bq; pa.b[1]=bk; pa.b[2]=bv;
  prep<<<12289,256,0,stream>>>(pa, wqkvT, w1T, w2T, bqkv);

  // LN1 -> xn
  ln_fwd<<<8192,256,0,stream>>>(x, ln1a, ln1b, xn);
  // QKV projection: [8192,3072]; q-slice scaled by QSCALE in epilogue (EPI=3)
  gemm256<3><<<dim3(32,12),512,0,stream>>>(xn, wqkvT, bqkv, qkv, 3072, 1024);
  // V -> vT[bh][d][s]
  v_transpose<<<dim3(32,64),256,0,stream>>>(qkv, vT);
  // attention -> ctx (MFMA flash, QT=256 per block, 8 waves)
  flash_attn_mfma<<<dim3(S_/256,H_,B_),512,0,stream>>>(qkv, vT, mask, ctx);
  // out projection + residual(x) -> h (stored in d_out, f32)
  gemm_bt<2><<<dim3(64,8),512,0,stream>>>(ctx, woT, bo, x, d_out, MROWS,1024,1024);
  // LN2 -> hn
  ln_fwd<<<8192,256,0,stream>>>((const float*)d_out, ln2a, ln2b, hn);
  // FFN1 + ReLU -> act
  gemm256<1><<<dim3(32,16),512,0,stream>>>(hn, w1T, b1, act, F_, 1024);
  // FFN2 + residual(h) -> d_out
  gemm_bt<2><<<dim3(64,8),512,0,stream>>>(act, w2T, b2, (const float*)d_out, d_out, MROWS,1024,F_);
}

// Round 7
// 526.354 us; speedup vs baseline: 1.0431x; 1.0015x over previous
//
#include <hip/hip_runtime.h>
#include <hip/hip_bf16.h>

typedef __attribute__((ext_vector_type(8))) short bf16x8;
typedef __attribute__((ext_vector_type(4))) short bf16x4;
typedef __attribute__((ext_vector_type(4))) float f32x4;
typedef __hip_bfloat16 bf16;
typedef unsigned short u16;

#define B_ 4
#define S_ 2048
#define D_ 1024
#define F_ 4096
#define H_ 16
#define MROWS 8192   // B_*S_
// 1/sqrt(dk) * log2(e), folded into the q-slice of the QKV GEMM epilogue
#define QSCALE 0.18033688011116012f

// ---------------- helpers ----------------
// pack 2 f32 -> 2 bf16 (round-half-up): 2 adds + 1 v_perm
__device__ __forceinline__ unsigned pkbf(float lo, float hi){
  union{float f; unsigned u;} a, b; a.f = lo; b.f = hi;
  return __builtin_amdgcn_perm(b.u + 0x8000u, a.u + 0x8000u, 0x07060302);
}
// single f32 -> bf16 bits (round-half-up): 2 VALU
__device__ __forceinline__ u16 bfrnd(float f){
  union{float ff; unsigned u;} c; c.ff = f;
  return (u16)((c.u + 0x8000u) >> 16);
}
// async global->LDS, 16B per lane; LDS dest = wave-uniform base + lane*16
__device__ __forceinline__ void gll16(const bf16* gp, u16* lp){
  __builtin_amdgcn_global_load_lds(
      (const __attribute__((address_space(1))) void*)gp,
      (__attribute__((address_space(3))) void*)lp, 16, 0, 0);
}

// ---------------- fused prep: 6 weight transposes + bias concat, ONE launch ----------------
// transpose semantics: W[K][N] f32 -> WT[N][K] bf16
struct PrepArgs { const float* w[6]; const float* b[3]; };
__global__ __launch_bounds__(256) void prep(
    PrepArgs pa, bf16* __restrict__ wqkvoT, bf16* __restrict__ w1T,
    bf16* __restrict__ w2T, float* __restrict__ bqkv)
{
  __shared__ float tl[32][33];
  const int bid = blockIdx.x, tid = threadIdx.x;
  const int x = tid&31, y = tid>>5;
  if (bid < 12288) {
    const float* W; bf16* dst; int K, N, nb, kb;
    if (bid < 4096)      { int wi=bid>>10, t=bid&1023; W=pa.w[wi]; dst=wqkvoT+(size_t)wi*1048576; K=1024; N=1024; nb=t&31;  kb=t>>5; }
    else if (bid < 8192) { int t=bid-4096;             W=pa.w[4];  dst=w1T;  K=1024; N=4096; nb=t&127; kb=t>>7; }
    else                 { int t=bid-8192;             W=pa.w[5];  dst=w2T;  K=4096; N=1024; nb=t&31;  kb=t>>5; }
    const int n0=nb*32, k0=kb*32;
    #pragma unroll
    for (int i=0;i<32;i+=8)
      tl[y+i][x] = W[(size_t)(k0+y+i)*N + n0+x];
    __syncthreads();
    #pragma unroll
    for (int i=0;i<32;i+=8)
      dst[(size_t)(n0+y+i)*K + k0+x] = __float2bfloat16(tl[x][y+i]);
  } else {
    for (int i=tid; i<3072; i+=256) bqkv[i] = pa.b[i>>10][i&1023];
  }
}

// ---------------- V transpose: qkv v-slice -> vT[bh][d][s] ----------------
__global__ __launch_bounds__(256) void v_transpose(
    const bf16* __restrict__ qkv, bf16* __restrict__ vT)
{
  __shared__ u16 tile[64*65];   // pitch 65 (odd) spreads banks for the column gather
  const int bh = blockIdx.y, b = bh>>4, h = bh&15;
  const int s0 = blockIdx.x*64;
  const int tid = threadIdx.x;
  const bf16* src = qkv + (size_t)(b*S_ + s0)*3072 + 2048 + h*64;
  #pragma unroll
  for (int i=0;i<2;i++){
    int idx = i*256 + tid;
    int r = idx>>3, sg = idx&7;
    uint4 v = *reinterpret_cast<const uint4*>(src + (size_t)r*3072 + sg*8);
    const u16* e = (const u16*)&v;
    #pragma unroll
    for (int j=0;j<8;j++) tile[r*65 + sg*8 + j] = e[j];
  }
  __syncthreads();
  bf16* dst = vT + (size_t)bh*64*S_ + s0;
  #pragma unroll
  for (int i=0;i<2;i++){
    int idx = i*256 + tid;
    int d = idx>>3, sg = idx&7;
    u16 tmp[8];
    #pragma unroll
    for (int j=0;j<8;j++) tmp[j] = tile[(sg*8+j)*65 + d];
    *reinterpret_cast<uint4*>(dst + (size_t)d*S_ + sg*8) = *reinterpret_cast<uint4*>(tmp);
  }
}

// ---------------- layernorm (torch-faithful: ddof=1, eps added to std) ----------------
__device__ __forceinline__ float block_reduce_256(float v, float* sbuf){
  #pragma unroll
  for (int o=32;o>0;o>>=1) v += __shfl_down(v, o);
  int wave = threadIdx.x>>6;
  if ((threadIdx.x&63)==0) sbuf[wave] = v;
  __syncthreads();
  float r = sbuf[0]+sbuf[1]+sbuf[2]+sbuf[3];
  __syncthreads();
  return r;
}

__global__ __launch_bounds__(256) void ln_fwd(
    const float* __restrict__ x, const float* __restrict__ alpha,
    const float* __restrict__ beta, bf16* __restrict__ out)
{
  __shared__ float sbuf[4];
  int row = blockIdx.x, tid = threadIdx.x;
  const float4* xr = reinterpret_cast<const float4*>(x + (size_t)row*D_);
  float4 v = xr[tid];
  float sum = block_reduce_256(v.x+v.y+v.z+v.w, sbuf);
  float mean = sum * (1.0f/1024.0f);
  float dx0=v.x-mean, dx1=v.y-mean, dx2=v.z-mean, dx3=v.w-mean;
  float ssq = block_reduce_256(dx0*dx0+dx1*dx1+dx2*dx2+dx3*dx3, sbuf);
  float std_ = sqrtf(ssq * (1.0f/1023.0f));        // ddof=1
  float inv = 1.0f/(std_ + 1e-6f);                 // eps added to std
  const float4* ar = reinterpret_cast<const float4*>(alpha);
  const float4* br = reinterpret_cast<const float4*>(beta);
  float4 a = ar[tid], bb = br[tid];
  unsigned* o = reinterpret_cast<unsigned*>(out + (size_t)row*D_);
  o[tid*2+0] = pkbf(a.x*dx0*inv + bb.x, a.y*dx1*inv + bb.y);
  o[tid*2+1] = pkbf(a.z*dx2*inv + bb.z, a.w*dx3*inv + bb.w);
}

// ---------------- GEMM: 512 threads, 128x128 tile, 8 waves of 64x32 (legacy fallback) ----------------
template<int EPI>
__global__ __launch_bounds__(512) void gemm_bt(
    const bf16* __restrict__ A, const bf16* __restrict__ BT,
    const float* __restrict__ bias, const float* __restrict__ res,
    void* __restrict__ out, int M, int N, int K)
{
  __shared__ __align__(16) u16 As[128*32];
  __shared__ __align__(16) u16 Bs[128*32];
  const int tid = threadIdx.x;
  const int m0 = blockIdx.x*128, n0 = blockIdx.y*128;
  const int wave = tid>>6, lane = tid&63;
  const int wm = (wave>>2)*64, wn = (wave&3)*32;
  const int lrow = lane&15, quad = lane>>4;
  const int srow = wave*16 + (lane>>2);
  const int sseg = lane&3;
  const bf16* apg = A  + (size_t)(m0+srow)*K + sseg*8;
  const bf16* bpg = BT + (size_t)(n0+srow)*K + sseg*8;
  u16* asd = &As[wave*512];
  u16* bsd = &Bs[wave*512];

  f32x4 acc[4][2];
  #pragma unroll
  for (int i=0;i<4;i++)
    #pragma unroll
    for (int j=0;j<2;j++) acc[i][j] = (f32x4){0.f,0.f,0.f,0.f};

  for (int k0=0; k0<K; k0+=32) {
    gll16(apg + k0, asd);
    gll16(bpg + k0, bsd);
    __syncthreads();
    bf16x8 a[4], b[2];
    #pragma unroll
    for (int t=0;t<4;t++)
      a[t] = *reinterpret_cast<const bf16x8*>(&As[(wm + t*16 + lrow)*32 + quad*8]);
    #pragma unroll
    for (int t=0;t<2;t++)
      b[t] = *reinterpret_cast<const bf16x8*>(&Bs[(wn + t*16 + lrow)*32 + quad*8]);
    #pragma unroll
    for (int mt=0;mt<4;mt++)
      #pragma unroll
      for (int nt=0;nt<2;nt++)
        acc[mt][nt] = __builtin_amdgcn_mfma_f32_16x16x32_bf16(a[mt], b[nt], acc[mt][nt], 0,0,0);
    __syncthreads();
  }

  #pragma unroll
  for (int mt=0;mt<4;mt++){
    #pragma unroll
    for (int nt=0;nt<2;nt++){
      int col = n0 + wn + nt*16 + lrow;
      float bv = bias[col];
      float sc = (EPI == 3 && col < 1024) ? QSCALE : 1.0f;
      #pragma unroll
      for (int r=0;r<4;r++){
        int row = m0 + wm + mt*16 + quad*4 + r;
        size_t idx = (size_t)row*N + col;
        float val = acc[mt][nt][r] + bv;
        if (EPI == 1) val = fmaxf(val, 0.0f);
        if (EPI == 3) val *= sc;
        if (EPI == 2) {
          ((float*)out)[idx] = val + res[idx];
        } else {
          ((u16*)out)[idx] = bfrnd(val);
        }
      }
    }
  }
}

// ---------------- GEMM 256x256, BK=64, 8-phase pipelined (m201-style template) ----------------
// (unchanged from round 4 — measured net win; see launcher)
#define LA256(bu,hf) (lds + (((bu)*2+0)*2+(hf))*8192)
#define LB256(bu,hf) (lds + (((bu)*2+1)*2+(hf))*8192)

__device__ __forceinline__ bf16x8 ldfrag(const u16* base, int row, int chunk){
  int pc = chunk ^ (row & 7);                       // T2 swizzle on read
  return *reinterpret_cast<const bf16x8*>(base + row*64 + pc*8);
}

__device__ __forceinline__ void stage_half256(const bf16* __restrict__ src, int K,
                                              u16* lbase, int wave, int lane){
  #pragma unroll
  for (int i=0;i<2;i++){
    int q = i*512 + wave*64 + lane;                 // physical 16B chunk index
    int row = q>>3;
    int seg = (q&7) ^ (row&7);                      // inverse swizzle on global source
    gll16(src + (size_t)row*K + seg*8, lbase + (i*512 + wave*64)*8);
  }
}

template<int RH, int KS, bool RB, typename STG, typename TAIL>
__device__ __forceinline__ void gphase(const u16* pa, const u16* pb, int bcol,
    int lr, int quad, bf16x8 (&b)[4][2], f32x4 (&acc)[8][4], STG stg, TAIL tail)
{
  bf16x8 a_[4];
  #pragma unroll
  for (int ar=0; ar<4; ar++)
    a_[ar] = ldfrag(pa, RH*64 + ar*16 + lr, KS*4 + quad);
  if constexpr (RB){
    #pragma unroll
    for (int cb=0; cb<4; cb++){
      b[cb][0] = ldfrag(pb, bcol + cb*16 + lr, quad);
      b[cb][1] = ldfrag(pb, bcol + cb*16 + lr, 4 + quad);
    }
  }
  stg();
  __builtin_amdgcn_s_barrier();
  asm volatile("s_waitcnt lgkmcnt(0)" ::: "memory");
  __builtin_amdgcn_sched_barrier(0);                // rule #18: keep MFMAs below the wait
  __builtin_amdgcn_s_setprio(1);
  #pragma unroll
  for (int ar=0; ar<4; ar++)
    #pragma unroll
    for (int cb=0; cb<4; cb++)
      acc[RH*4+ar][cb] = __builtin_amdgcn_mfma_f32_16x16x32_bf16(a_[ar], b[cb][KS], acc[RH*4+ar][cb], 0,0,0);
  __builtin_amdgcn_s_setprio(0);
  tail();
  __builtin_amdgcn_s_barrier();
}

// EPI: 1=bf16+ReLU (FFN1), 3=bf16 with cols<1024 scaled by QSCALE (QKV). M fixed = MROWS.
template<int EPI>
__global__ __launch_bounds__(512) void gemm256(
    const bf16* __restrict__ A, const bf16* __restrict__ BT,
    const float* __restrict__ bias, bf16* __restrict__ out, int N, int K)
{
  __shared__ __align__(16) u16 lds[65536];          // 131072 B static (gfx950: 160 KiB LDS)
  const int tid = threadIdx.x, wave = tid>>6, lane = tid&63;
  const int wr = wave>>2, wc = wave&3;              // 2M x 4N wave grid
  const int lr = lane&15, quad = lane>>4;
  const int gx = gridDim.x;
  const int nwg = gx*gridDim.y;
  int flat = blockIdx.y*gx + blockIdx.x;
  int cpx = nwg>>3;
  int swz = (flat&7)*cpx + (flat>>3);
  const int m0 = (swz % gx)*256, n0 = (swz / gx)*256;
  const int T = K>>6;

  const bf16* Ag = A  + (size_t)m0*K;
  const bf16* Bg = BT + (size_t)n0*K;
  const int bcol = (wc&1)*64;

  f32x4 acc[8][4];
  #pragma unroll
  for (int i=0;i<8;i++)
    #pragma unroll
    for (int j=0;j<4;j++) acc[i][j] = (f32x4){0.f,0.f,0.f,0.f};

  // prologue: tile0 (4 halves) + B halves of tile1; allow B(1) in flight
  stage_half256(Ag,                       K, LA256(0,0), wave, lane);
  stage_half256(Ag + (size_t)128*K,       K, LA256(0,1), wave, lane);
  stage_half256(Bg,                       K, LB256(0,0), wave, lane);
  stage_half256(Bg + (size_t)128*K,       K, LB256(0,1), wave, lane);
  stage_half256(Bg + 64,                  K, LB256(1,0), wave, lane);
  stage_half256(Bg + (size_t)128*K + 64,  K, LB256(1,1), wave, lane);
  asm volatile("s_waitcnt vmcnt(4)" ::: "memory");
  __builtin_amdgcn_s_barrier();

  for (int t=0; t<T; ++t){
    const int bu = t&1, nbu = bu^1;
    const u16* pa = LA256(bu, wr);
    const u16* pb = LB256(bu, wc>>1);
    const size_t ktA = (size_t)((t+1 < T) ? t+1 : T-1)*64;   // clamp keeps vmcnt counts uniform
    const size_t ktB = (size_t)((t+2 < T) ? t+2 : T-1)*64;
    bf16x8 b[4][2];
    gphase<0,0,true >(pa, pb, bcol, lr, quad, b, acc,
        [&]{ stage_half256(Ag + ktA,                 K, LA256(nbu,0), wave, lane); }, [&]{});
    gphase<1,0,false>(pa, pb, bcol, lr, quad, b, acc,
        [&]{ stage_half256(Ag + (size_t)128*K + ktA, K, LA256(nbu,1), wave, lane); }, [&]{});
    gphase<0,1,false>(pa, pb, bcol, lr, quad, b, acc,
        [&]{ stage_half256(Bg + ktB,                 K, LB256(bu,0),  wave, lane); }, [&]{});
    gphase<1,1,false>(pa, pb, bcol, lr, quad, b, acc,
        [&]{ stage_half256(Bg + (size_t)128*K + ktB, K, LB256(bu,1),  wave, lane); },
        [&]{ asm volatile("s_waitcnt vmcnt(4)" ::: "memory"); });
  }

  // epilogue
  #pragma unroll
  for (int mi=0; mi<8; mi++){
    const int row0 = m0 + wr*128 + (mi>>2)*64 + (mi&3)*16 + quad*4;
    #pragma unroll
    for (int cb=0; cb<4; cb++){
      const int col = n0 + wc*64 + cb*16 + lr;
      float bv = bias[col];
      float sc = (EPI==3 && col < 1024) ? QSCALE : 1.0f;
      #pragma unroll
      for (int r=0; r<4; r++){
        float val = acc[mi][cb][r] + bv;
        if (EPI == 1) val = fmaxf(val, 0.0f);
        if (EPI == 3) val *= sc;
        ((u16*)out)[(size_t)(row0+r)*N + col] = bfrnd(val);
      }
    }
  }
}

// ---------------- GEMM 256x128, BK=64, 8-phase, f32+residual epilogue (Wo / FFN2) ----------------
// N=1024 shapes: grid 32x8 = 256 blocks = exactly 1/CU. 8 waves (2M x 4N), per-wave 128x32.
// LDS 96 KiB static: [dbuf][ A-half0 | A-half1 | B ] x 8192 u16. Same T2 chunk-XOR swizzle.
// Stagger: P1 stage A0(t+1), P2 stage A1(t+1) (other buf); P3 stage B(t+2) (current buf,
// B last read at this tile's P1); P4: vmcnt(2) leaves exactly B(t+2)'s 2 loads in flight.
#define LA2(bu,hf) (lds2 + ((bu)*3+(hf))*8192)
#define LB2(bu)    (lds2 + ((bu)*3+2)*8192)

template<int RH, int KS, bool RB, typename STG, typename TAIL>
__device__ __forceinline__ void gphase2(const u16* pa, const u16* pb, int bcol,
    int lr, int quad, bf16x8 (&b)[2][2], f32x4 (&acc)[8][2], STG stg, TAIL tail)
{
  bf16x8 a_[4];
  #pragma unroll
  for (int ar=0; ar<4; ar++)
    a_[ar] = ldfrag(pa, RH*64 + ar*16 + lr, KS*4 + quad);
  if constexpr (RB){
    #pragma unroll
    for (int cb=0; cb<2; cb++){
      b[cb][0] = ldfrag(pb, bcol + cb*16 + lr, quad);
      b[cb][1] = ldfrag(pb, bcol + cb*16 + lr, 4 + quad);
    }
  }
  stg();
  __builtin_amdgcn_s_barrier();
  asm volatile("s_waitcnt lgkmcnt(0)" ::: "memory");
  __builtin_amdgcn_sched_barrier(0);
  __builtin_amdgcn_s_setprio(1);
  #pragma unroll
  for (int ar=0; ar<4; ar++)
    #pragma unroll
    for (int cb=0; cb<2; cb++)
      acc[RH*4+ar][cb] = __builtin_amdgcn_mfma_f32_16x16x32_bf16(a_[ar], b[cb][KS], acc[RH*4+ar][cb], 0,0,0);
  __builtin_amdgcn_s_setprio(0);
  tail();
  __builtin_amdgcn_s_barrier();
}

__global__ __launch_bounds__(512) void gemm256r(
    const bf16* __restrict__ A, const bf16* __restrict__ BT,
    const float* __restrict__ bias, const float* __restrict__ res,
    float* __restrict__ out, int N, int K)
{
  __shared__ __align__(16) u16 lds2[49152];         // 96 KiB static
  const int tid = threadIdx.x, wave = tid>>6, lane = tid&63;
  const int wr = wave>>2, wc = wave&3;              // 2M x 4N wave grid
  const int lr = lane&15, quad = lane>>4;
  const int gx = gridDim.x;
  const int nwg = gx*gridDim.y;
  int flat = blockIdx.y*gx + blockIdx.x;
  int cpx = nwg>>3;
  int swz = (flat&7)*cpx + (flat>>3);
  const int m0 = (swz % gx)*256, n0 = (swz / gx)*128;
  const int T = K>>6;

  const bf16* Ag = A  + (size_t)m0*K;
  const bf16* Bg = BT + (size_t)n0*K;
  const int bcol = wc*32;

  f32x4 acc[8][2];
  #pragma unroll
  for (int i=0;i<8;i++)
    #pragma unroll
    for (int j=0;j<2;j++) acc[i][j] = (f32x4){0.f,0.f,0.f,0.f};

  // prologue: A(0) both halves, B(0), B(1); leave B(1) in flight
  stage_half256(Ag,                 K, LA2(0,0), wave, lane);
  stage_half256(Ag + (size_t)128*K, K, LA2(0,1), wave, lane);
  stage_half256(Bg,                 K, LB2(0),   wave, lane);
  stage_half256(Bg + 64,            K, LB2(1),   wave, lane);
  asm volatile("s_waitcnt vmcnt(2)" ::: "memory");
  __builtin_amdgcn_s_barrier();

  for (int t=0; t<T; ++t){
    const int bu = t&1, nbu = bu^1;
    const u16* pa = LA2(bu, wr);
    const u16* pb = LB2(bu);
    const size_t ktA = (size_t)((t+1 < T) ? t+1 : T-1)*64;
    const size_t ktB = (size_t)((t+2 < T) ? t+2 : T-1)*64;
    bf16x8 b[2][2];
    gphase2<0,0,true >(pa, pb, bcol, lr, quad, b, acc,
        [&]{ stage_half256(Ag + ktA,                 K, LA2(nbu,0), wave, lane); }, [&]{});
    gphase2<1,0,false>(pa, pb, bcol, lr, quad, b, acc,
        [&]{ stage_half256(Ag + (size_t)128*K + ktA, K, LA2(nbu,1), wave, lane); }, [&]{});
    gphase2<0,1,false>(pa, pb, bcol, lr, quad, b, acc,
        [&]{ stage_half256(Bg + ktB,                 K, LB2(bu),    wave, lane); }, [&]{});
    gphase2<1,1,false>(pa, pb, bcol, lr, quad, b, acc,
        [&]{}, [&]{ asm volatile("s_waitcnt vmcnt(2)" ::: "memory"); });
  }

  // epilogue: f32 + bias + residual
  #pragma unroll
  for (int mi=0; mi<8; mi++){
    const int row0 = m0 + wr*128 + (mi>>2)*64 + (mi&3)*16 + quad*4;
    #pragma unroll
    for (int cb=0; cb<2; cb++){
      const int col = n0 + bcol + cb*16 + lr;
      float bv = bias[col];
      #pragma unroll
      for (int r=0; r<4; r++){
        size_t idx = (size_t)(row0+r)*N + col;
        out[idx] = acc[mi][cb][r] + bv + res[idx];
      }
    }
  }
}

// ---------------- MFMA flash attention: S^T trick, QT=256, 8 waves (round-0 version) ----------------
#define KP 72   // LDS pitch: 144B rows, 16B-aligned for b128

__global__ __launch_bounds__(512) void flash_attn_mfma(
    const bf16* __restrict__ qkv, const bf16* __restrict__ vT,
    const int* __restrict__ mask, bf16* __restrict__ ctx)
{
  __shared__ __align__(16) u16 Ks[64*KP];       // K[key][d]
  __shared__ __align__(16) u16 Vt[64*KP];       // V^T[d][key]
  __shared__ __align__(16) float Mb[64];        // mask bias (slow path only)

  const int b = blockIdx.z, h = blockIdx.y, qt = blockIdx.x;
  const int tid = threadIdx.x, wave = tid>>6, lane = tid&63;
  const int lr = lane&15, quad = lane>>4;
  const int qbase = qt*256 + wave*32;           // 32 q-rows per wave (2 q-sets of 16)

  const bf16* base = qkv + (size_t)b*S_*3072 + h*64;
  const bf16* vtb  = vT + (size_t)(b*H_+h)*64*S_;
  const int*  mrow = mask + b*S_;

  bf16x8 qf[2][2];
  #pragma unroll
  for (int c=0;c<2;c++){
    const bf16* qp = base + (size_t)(qbase + c*16 + lr)*3072 + quad*8;
    qf[c][0] = *reinterpret_cast<const bf16x8*>(qp);
    qf[c][1] = *reinterpret_cast<const bf16x8*>(qp + 32);
  }

  const bf16x4 ones4 = {(short)0x3F80,(short)0x3F80,(short)0x3F80,(short)0x3F80};

  f32x4 actx[2][4];                              // [c][dt] : ctx^T[d=dt*16+quad*4+r][q=c*16+lr]
  f32x4 acc_l[2];                                // l per q (rows identical)
  #pragma unroll
  for (int c=0;c<2;c++){
    #pragma unroll
    for (int dt=0;dt<4;dt++) actx[c][dt] = (f32x4){0.f,0.f,0.f,0.f};
    acc_l[c] = (f32x4){0.f,0.f,0.f,0.f};
  }

  const int sr = tid>>3, sg = tid&7;

  for (int kt=0; kt<S_; kt+=64){
    *reinterpret_cast<uint4*>(&Ks[sr*KP + sg*8]) =
      *reinterpret_cast<const uint4*>(base + 1024 + (size_t)(kt+sr)*3072 + sg*8);
    *reinterpret_cast<uint4*>(&Vt[sr*KP + sg*8]) =
      *reinterpret_cast<const uint4*>(vtb + (size_t)sr*S_ + kt + sg*8);
    if (tid < 64) Mb[tid] = (mrow[kt+tid]==0) ? -2e9f : 0.0f;
    unsigned long long bal = __ballot(mrow[kt + lane] == 0);
    __syncthreads();

    bf16x4 pk[2][4];                             // [c][nt] : keys nt*16+quad*4+j, q=c*16+lr
    if (bal == 0ULL) {
      #pragma unroll
      for (int nt=0;nt<4;nt++){
        bf16x8 kf0 = *reinterpret_cast<const bf16x8*>(&Ks[(nt*16+lr)*KP + quad*8]);
        bf16x8 kf1 = *reinterpret_cast<const bf16x8*>(&Ks[(nt*16+lr)*KP + 32 + quad*8]);
        #pragma unroll
        for (int c=0;c<2;c++){
          f32x4 a = (f32x4){0.f,0.f,0.f,0.f};
          a = __builtin_amdgcn_mfma_f32_16x16x32_bf16(kf0, qf[c][0], a, 0,0,0);
          a = __builtin_amdgcn_mfma_f32_16x16x32_bf16(kf1, qf[c][1], a, 0,0,0);
          uint2 w;
          w.x = pkbf(__builtin_amdgcn_exp2f(a[0]), __builtin_amdgcn_exp2f(a[1]));
          w.y = pkbf(__builtin_amdgcn_exp2f(a[2]), __builtin_amdgcn_exp2f(a[3]));
          union{uint2 u; bf16x4 v;} cvt; cvt.u = w;
          pk[c][nt] = cvt.v;
        }
      }
    } else {
      #pragma unroll
      for (int nt=0;nt<4;nt++){
        bf16x8 kf0 = *reinterpret_cast<const bf16x8*>(&Ks[(nt*16+lr)*KP + quad*8]);
        bf16x8 kf1 = *reinterpret_cast<const bf16x8*>(&Ks[(nt*16+lr)*KP + 32 + quad*8]);
        float4 mb = *reinterpret_cast<const float4*>(&Mb[nt*16 + quad*4]);
        #pragma unroll
        for (int c=0;c<2;c++){
          f32x4 a = (f32x4){0.f,0.f,0.f,0.f};
          a = __builtin_amdgcn_mfma_f32_16x16x32_bf16(kf0, qf[c][0], a, 0,0,0);
          a = __builtin_amdgcn_mfma_f32_16x16x32_bf16(kf1, qf[c][1], a, 0,0,0);
          uint2 w;
          w.x = pkbf(__builtin_amdgcn_exp2f(a[0]+mb.x), __builtin_amdgcn_exp2f(a[1]+mb.y));
          w.y = pkbf(__builtin_amdgcn_exp2f(a[2]+mb.z), __builtin_amdgcn_exp2f(a[3]+mb.w));
          union{uint2 u; bf16x4 v;} cvt; cvt.u = w;
          pk[c][nt] = cvt.v;
        }
      }
    }

    // ---- ctx^T += V^T P^T ; l += 1^T P (both on MFMA pipe) ----
    #pragma unroll
    for (int dt=0;dt<4;dt++){
      #pragma unroll
      for (int kc=0;kc<4;kc++){
        bf16x4 vf = *reinterpret_cast<const bf16x4*>(&Vt[(dt*16+lr)*KP + kc*16 + quad*4]);
        #pragma unroll
        for (int c=0;c<2;c++)
          actx[c][dt] = __builtin_amdgcn_mfma_f32_16x16x16bf16_1k(vf, pk[c][kc], actx[c][dt], 0,0,0);
      }
    }
    #pragma unroll
    for (int kc=0;kc<4;kc++)
      #pragma unroll
      for (int c=0;c<2;c++)
        acc_l[c] = __builtin_amdgcn_mfma_f32_16x16x16bf16_1k(ones4, pk[c][kc], acc_l[c], 0,0,0);
    __syncthreads();
  }

  #pragma unroll
  for (int c=0;c<2;c++){
    float inv = 1.0f/acc_l[c][0];
    int q = qbase + c*16 + lr;
    bf16* op = ctx + (size_t)(b*S_+q)*D_ + h*64 + quad*4;
    #pragma unroll
    for (int dt=0;dt<4;dt++){
      uint2 o;
      o.x = pkbf(actx[c][dt][0]*inv, actx[c][dt][1]*inv);
      o.y = pkbf(actx[c][dt][2]*inv, actx[c][dt][3]*inv);
      *reinterpret_cast<uint2*>(op + dt*16) = o;
    }
  }
}

// ---------------- launch ----------------
extern "C" void kernel_launch(void* const* d_in, const int* in_sizes, int n_in,
                              void* d_out, int out_size, void* d_ws, size_t ws_size,
                              hipStream_t stream) {
  const float* x    = (const float*)d_in[0];
  const int*   mask = (const int*)  d_in[1];
  const float* wq   = (const float*)d_in[2];
  const float* bq   = (const float*)d_in[3];
  const float* wk   = (const float*)d_in[4];
  const float* bk   = (const float*)d_in[5];
  const float* wv   = (const float*)d_in[6];
  const float* bv   = (const float*)d_in[7];
  const float* wo   = (const float*)d_in[8];
  const float* bo   = (const float*)d_in[9];
  const float* w1   = (const float*)d_in[10];
  const float* b1   = (const float*)d_in[11];
  const float* w2   = (const float*)d_in[12];
  const float* b2   = (const float*)d_in[13];
  const float* ln1a = (const float*)d_in[14];
  const float* ln1b = (const float*)d_in[15];
  const float* ln2a = (const float*)d_in[16];
  const float* ln2b = (const float*)d_in[17];

  char* ws = (char*)d_ws;
  bf16*  wqkvT = (bf16*) (ws + 0);                 //  6 MB [3072][1024]
  bf16*  woT   = (bf16*) (ws + 6291456);           //  2 MB [1024][1024]
  bf16*  w1T   = (bf16*) (ws + 8388608);           //  8 MB [4096][1024]
  bf16*  w2T   = (bf16*) (ws + 16777216);          //  8 MB [1024][4096]
  float* bqkv  = (float*)(ws + 25165824);          // 12 KB [3072]
  bf16*  xn    = (bf16*) (ws + 25178112);          // 16 MB [8192][1024] (dead after QKV gemm)
  bf16*  vT    = (bf16*) (ws + 25178112);          // 16 MB [64][64][2048], reuses xn slot
  bf16*  qkv   = (bf16*) (ws + 41955328);          // 48 MB [8192][3072]
  bf16*  ctx   = (bf16*) (ws + 92286976);          // 16 MB [8192][1024]
  bf16*  hn    = (bf16*) (ws + 109064192);         // 16 MB [8192][1024]
  bf16*  act   = (bf16*) (ws + 25178112);          // 64 MB [8192][4096], aliases vT+qkv (dead by then)

  PrepArgs pa;
  pa.w[0]=wq; pa.w[1]=wk; pa.w[2]=wv; pa.w[3]=wo; pa.w[4]=w1; pa.w[5]=w2;
  pa.b[0]=bq; pa.b[1]=bk; pa.b[2]=bv;
  prep<<<12289,256,0,stream>>>(pa, wqkvT, w1T, w2T, bqkv);

  // LN1 -> xn
  ln_fwd<<<8192,256,0,stream>>>(x, ln1a, ln1b, xn);
  // QKV projection: [8192,3072]; q-slice scaled by QSCALE in epilogue (EPI=3)
  gemm256<3><<<dim3(32,12),512,0,stream>>>(xn, wqkvT, bqkv, qkv, 3072, 1024);
  // V -> vT[bh][d][s]
  v_transpose<<<dim3(32,64),256,0,stream>>>(qkv, vT);
  // attention -> ctx (MFMA flash, QT=256 per block, 8 waves)
  flash_attn_mfma<<<dim3(S_/256,H_,B_),512,0,stream>>>(qkv, vT, mask, ctx);
  // out projection + residual(x) -> h (stored in d_out, f32): 8-phase 256x128
  gemm256r<<<dim3(32,8),512,0,stream>>>(ctx, woT, bo, x, (float*)d_out, 1024, 1024);
  // LN2 -> hn
  ln_fwd<<<8192,256,0,stream>>>((const float*)d_out, ln2a, ln2b, hn);
  // FFN1 + ReLU -> act
  gemm256<1><<<dim3(32,16),512,0,stream>>>(hn, w1T, b1, act, F_, 1024);
  // FFN2 + residual(h) -> d_out: 8-phase 256x128, K=4096
  gemm256r<<<dim3(32,8),512,0,stream>>>(act, w2T, b2, (const float*)d_out, (float*)d_out, 1024, 4096);
}